// Round 15
// baseline (559.981 us; speedup 1.0000x reference)
//
#include <hip/hip_runtime.h>

#define NN 100000
#define EE 3200000
#define HH 128
#define CC 40
#define KK 5
#define NBUK 391   // ceil(NN/256) buckets of 256 nodes
#define CH 8192    // edges per coarse-scatter block
#define CH2 16384  // edges per bucket-hist block

typedef __attribute__((ext_vector_type(8))) short bf16x8;
typedef __attribute__((ext_vector_type(4))) float f32x4;

__device__ inline float b2f(unsigned short u) {
    union { unsigned int i; float f; } c;
    c.i = ((unsigned int)u) << 16;
    return c.f;
}
__device__ inline float b2f_lo(unsigned int u) {
    union { unsigned int i; float f; } c;
    c.i = u << 16;
    return c.f;
}
__device__ inline float b2f_hi(unsigned int u) {
    union { unsigned int i; float f; } c;
    c.i = u & 0xFFFF0000u;
    return c.f;
}
__device__ inline unsigned short f2b(float f) {
    union { float f; unsigned int i; } c;
    c.f = f;
    unsigned int r = c.i + 0x7FFFu + ((c.i >> 16) & 1u);
    return (unsigned short)(r >> 16);
}

// ---------------------------------------------------------------- CSR build
// Per-bucket degrees via LDS-aggregated histogram (391 buckets of 256 nodes).
__global__ __launch_bounds__(512) void bucket_hist_kernel(const int* __restrict__ dst,
                                                          int* __restrict__ bdeg) {
    __shared__ int h[512];
    int t = threadIdx.x;
    h[t] = 0;
    __syncthreads();
    int base = blockIdx.x * CH2;
    int end = base + CH2;
    if (end > EE) end = EE;
    for (int e = base + t; e < end; e += 512) atomicAdd(&h[dst[e] >> 8], 1);
    __syncthreads();
    int v = h[t];
    if (v > 0) atomicAdd(&bdeg[t], v);
}

// Single block: scan bucket degrees -> bucket bases + coarse cursors;
// also offsets[NN]=EE and the two hop-weight softmaxes.
__global__ void bucket_scan_kernel(const int* __restrict__ bdeg, int* __restrict__ bbase,
                                   int* __restrict__ gcur, int* __restrict__ offsets,
                                   const float* __restrict__ hc0, const float* __restrict__ hc1,
                                   float* __restrict__ wsm) {
    __shared__ int sh[512];
    int t = threadIdx.x;
    int v = (t < NBUK) ? bdeg[t] : 0;
    sh[t] = v;
    __syncthreads();
    for (int off = 1; off < 512; off <<= 1) {
        int x = (t >= off) ? sh[t - off] : 0;
        __syncthreads();
        sh[t] += x;
        __syncthreads();
    }
    if (t < NBUK) {
        int b = sh[t] - v;  // exclusive prefix
        bbase[t] = b;
        gcur[t] = b;
    }
    if (t == 0) {
        bbase[NBUK] = EE;
        offsets[NN] = EE;
        for (int which = 0; which < 2; ++which) {
            const float* hc = which ? hc1 : hc0;
            float mx = hc[0];
            for (int k = 1; k < KK; ++k) mx = fmaxf(mx, hc[k]);
            float ex0 = expf(hc[0] - mx), ex1 = expf(hc[1] - mx), ex2 = expf(hc[2] - mx);
            float ex3 = expf(hc[3] - mx), ex4 = expf(hc[4] - mx);
            float inv = 1.0f / (ex0 + ex1 + ex2 + ex3 + ex4);
            wsm[which * 8 + 0] = ex0 * inv;
            wsm[which * 8 + 1] = ex1 * inv;
            wsm[which * 8 + 2] = ex2 * inv;
            wsm[which * 8 + 3] = ex3 * inv;
            wsm[which * 8 + 4] = ex4 * inv;
        }
    }
}

// Coarse scatter: bin edges into NBUK buckets (dst>>8) with LDS staging so
// global writes are consecutive runs (line-merged) instead of random 4B.
// Payload: src(17b) | dist<<17 (3b) | (dst&255)<<20 (8b).
__global__ __launch_bounds__(512) void coarse_scatter_kernel(const int* __restrict__ src,
                                                             const int* __restrict__ dst,
                                                             const int* __restrict__ dist,
                                                             int* __restrict__ gcur,
                                                             int* __restrict__ coarse) {
    __shared__ int cnt[512];
    __shared__ int scn[512];
    __shared__ int lofs[512];
    __shared__ int gb[512];
    __shared__ int staging[CH];
    __shared__ int tgt[CH];
    int t = threadIdx.x;
    int base = blockIdx.x * CH;

    cnt[t] = 0;
    __syncthreads();

    int val[16], bb[16];
#pragma unroll
    for (int jj = 0; jj < 16; ++jj) {
        int e = base + jj * 512 + t;
        if (e < EE) {
            int d = dst[e];
            int b = d >> 8;
            bb[jj] = b;
            val[jj] = src[e] | (dist[e] << 17) | ((d & 255) << 20);
            atomicAdd(&cnt[b], 1);
        } else {
            bb[jj] = -1;
            val[jj] = 0;
        }
    }
    __syncthreads();

    int c = cnt[t];
    scn[t] = c;
    __syncthreads();
    for (int off = 1; off < 512; off <<= 1) {
        int x = (t >= off) ? scn[t - off] : 0;
        __syncthreads();
        scn[t] += x;
        __syncthreads();
    }
    lofs[t] = scn[t] - c;
    if (t < NBUK && c > 0) gb[t] = atomicAdd(&gcur[t], c);
    cnt[t] = 0;  // reuse as second counter
    __syncthreads();

#pragma unroll
    for (int jj = 0; jj < 16; ++jj) {
        int b = bb[jj];
        if (b >= 0) {
            int pos = atomicAdd(&cnt[b], 1);
            int slot = lofs[b] + pos;
            staging[slot] = val[jj];
            tgt[slot] = gb[b] + pos;
        }
    }
    __syncthreads();

    int total = scn[511];
    for (int j = t; j < total; j += 512) coarse[tgt[j]] = staging[j];
}

// Fine scatter v2: one block per bucket. Pass A: LDS histogram of the 256
// in-bucket node slots + LDS scan -> per-node CSR offsets (written to global).
// Pass B: scatter via LDS cursors. No global per-node atomics anywhere.
__global__ __launch_bounds__(512) void fine_scatter_kernel(const int* __restrict__ coarse,
                                                           const int* __restrict__ bbase,
                                                           int* __restrict__ offsets,
                                                           int* __restrict__ sorted) {
    __shared__ int cnt[256];
    __shared__ int scn[256];
    __shared__ int cur[256];
    int b = blockIdx.x;
    int t = threadIdx.x;
    if (t < 256) cnt[t] = 0;
    __syncthreads();
    int sb = bbase[b], se = bbase[b + 1];
    for (int idx = sb + t; idx < se; idx += 512)
        atomicAdd(&cnt[(coarse[idx] >> 20) & 255], 1);
    __syncthreads();
    int c = (t < 256) ? cnt[t] : 0;
    if (t < 256) scn[t] = c;
    __syncthreads();
    for (int off = 1; off < 256; off <<= 1) {
        int x = 0;
        if (t < 256 && t >= off) x = scn[t - off];
        __syncthreads();
        if (t < 256) scn[t] += x;
        __syncthreads();
    }
    if (t < 256) {
        int pos = sb + scn[t] - c;  // exclusive prefix within bucket
        int node = (b << 8) + t;
        if (node < NN) offsets[node] = pos;
        cur[t] = pos;
    }
    __syncthreads();
    for (int idx = sb + t; idx < se; idx += 512) {
        int v = coarse[idx];
        int p = atomicAdd(&cur[(v >> 20) & 255], 1);
        sorted[p] = (v & 0x1FFFF) | (((v >> 17) & 7) << 20);  // src | dist<<20
    }
}

// ---------------------------------------------------------------- converts

// transpose + bf16-convert all 7 weights: dst[wi][n][k] = W[wi][k][n]
__global__ __launch_bounds__(256) void prep_w_kernel(const float* W0, const float* W1,
                                                     const float* W2, const float* W3,
                                                     const float* W4, const float* W5,
                                                     const float* W6,
                                                     unsigned short* __restrict__ dst) {
    int idx = blockIdx.x * 256 + threadIdx.x;
    if (idx >= 7 * 16384) return;
    int wi = idx / 16384, r = idx - wi * 16384;
    int n = r & 127, k = r >> 7;
    const float* W = wi == 0 ? W0 : wi == 1 ? W1 : wi == 2 ? W2 : wi == 3 ? W3
                   : wi == 4 ? W4 : wi == 5 ? W5 : W6;
    int ncol = (wi == 6) ? CC : 128;
    float v = (n < ncol) ? W[k * ncol + n] : 0.f;
    dst[wi * 16384 + n * 128 + k] = f2b(v);
}

// ------------------------------------------------------------------- GEMM
// U = (TRANSFORM ? relu(a*Z+d) : Z) @ W + bias  on bf16 inputs, fp32 MFMA accum.
// TRANSFORM: (a,d) computed in-block from statsIn/gvec/bvec (folded bn_finalize,
//            bit-identical math; abS scratch lives in Ws before W staging).
// CVTIN: Zin is fp32 (the raw x input), converted to bf16 during LDS staging.

template <int NT, bool TRANSFORM, bool STATS, bool OUTF32, bool CVTIN>
__global__ __launch_bounds__(256) void mfma_gemm(const void* __restrict__ ZinV,
                                                 const unsigned short* __restrict__ Wt,
                                                 const float* __restrict__ bias, int ncol_real,
                                                 const float* __restrict__ statsIn,
                                                 const float* __restrict__ gvec,
                                                 const float* __restrict__ bvec,
                                                 void* __restrict__ Uout,
                                                 float* __restrict__ stats) {
    __shared__ unsigned short Zs[128 * 128];
    __shared__ unsigned short Ws[NT * 16 * 128];
    int t = threadIdx.x;
    int m0 = blockIdx.x * 128;
    int c8 = t & 15;  // 16B chunk (8 bf16) within a 128-elem row

    float av[8], dv[8];
    if constexpr (TRANSFORM) {
        float* abS = (float*)Ws;  // scratch; overwritten by W staging later
        if (t < 128) {
            float s = 0.f, s2 = 0.f;
            for (int k = 0; k < 32; ++k) {
                s += statsIn[k * 256 + t];
                s2 += statsIn[k * 256 + 128 + t];
            }
            float m = s * (1.0f / NN);
            float var = s2 * (1.0f / NN) - m * m;
            float a = gvec[t] * rsqrtf(var + 1e-5f);
            abS[t] = a;
            abS[128 + t] = bvec[t] - a * m;
        }
        __syncthreads();
#pragma unroll
        for (int j = 0; j < 8; ++j) {
            av[j] = abS[c8 * 8 + j];
            dv[j] = abS[128 + c8 * 8 + j];
        }
        __syncthreads();
    }
    // stage A
#pragma unroll
    for (int it = 0; it < 8; ++it) {
        int chunk = it * 256 + t;
        int r = chunk >> 4;
        int gr = m0 + r;
        bf16x8 v = {};
        if constexpr (CVTIN) {
            const float* Zf = (const float*)ZinV;
            if (gr < NN) {
                float4 f0 = *(const float4*)(Zf + (size_t)gr * 128 + c8 * 8);
                float4 f1 = *(const float4*)(Zf + (size_t)gr * 128 + c8 * 8 + 4);
                v[0] = (short)f2b(f0.x); v[1] = (short)f2b(f0.y);
                v[2] = (short)f2b(f0.z); v[3] = (short)f2b(f0.w);
                v[4] = (short)f2b(f1.x); v[5] = (short)f2b(f1.y);
                v[6] = (short)f2b(f1.z); v[7] = (short)f2b(f1.w);
            }
        } else {
            const unsigned short* Zin = (const unsigned short*)ZinV;
            if (gr < NN) v = *(const bf16x8*)(Zin + (size_t)gr * 128 + c8 * 8);
            if constexpr (TRANSFORM) {
#pragma unroll
                for (int j = 0; j < 8; ++j) {
                    float f = fmaxf(0.f, fmaf(av[j], b2f((unsigned short)v[j]), dv[j]));
                    v[j] = (short)f2b(f);
                }
            }
        }
        int ks = c8 * 8;
        *(bf16x8*)(&Zs[r * 128 + (ks ^ ((r & 7) << 3))]) = v;
    }
    // stage W^T
    for (int chunk = t; chunk < NT * 16 * 16; chunk += 256) {
        int r = chunk >> 4, cc = chunk & 15;
        bf16x8 v = *(const bf16x8*)(Wt + r * 128 + cc * 8);
        int ks = cc * 8;
        *(bf16x8*)(&Ws[r * 128 + (ks ^ ((r & 7) << 3))]) = v;
    }
    __syncthreads();

    int l = t & 63, w = t >> 6;
    int lr = l & 15, lg = l >> 4;

    f32x4 acc[2][NT];
#pragma unroll
    for (int mt = 0; mt < 2; ++mt)
#pragma unroll
        for (int nt = 0; nt < NT; ++nt) acc[mt][nt] = (f32x4){0.f, 0.f, 0.f, 0.f};

#pragma unroll
    for (int kc = 0; kc < 4; ++kc) {
        int ks = kc * 32 + lg * 8;
        bf16x8 afr[2];
#pragma unroll
        for (int mt = 0; mt < 2; ++mt) {
            int row = w * 32 + mt * 16 + lr;
            afr[mt] = *(const bf16x8*)(&Zs[row * 128 + (ks ^ ((row & 7) << 3))]);
        }
#pragma unroll
        for (int nt = 0; nt < NT; ++nt) {
            int n = nt * 16 + lr;
            bf16x8 bfr = *(const bf16x8*)(&Ws[n * 128 + (ks ^ ((n & 7) << 3))]);
            acc[0][nt] = __builtin_amdgcn_mfma_f32_16x16x32_bf16(afr[0], bfr, acc[0][nt], 0, 0, 0);
            acc[1][nt] = __builtin_amdgcn_mfma_f32_16x16x32_bf16(afr[1], bfr, acc[1][nt], 0, 0, 0);
        }
    }

    float bv[NT];
#pragma unroll
    for (int nt = 0; nt < NT; ++nt) {
        int col = nt * 16 + lr;
        bv[nt] = (col < ncol_real) ? bias[col] : 0.f;
    }
    float s1[NT], s2[NT];
    if constexpr (STATS) {
#pragma unroll
        for (int nt = 0; nt < NT; ++nt) { s1[nt] = 0.f; s2[nt] = 0.f; }
    }

#pragma unroll
    for (int mt = 0; mt < 2; ++mt) {
#pragma unroll
        for (int j = 0; j < 4; ++j) {
            int row = m0 + w * 32 + mt * 16 + lg * 4 + j;
            bool rv = row < NN;
#pragma unroll
            for (int nt = 0; nt < NT; ++nt) {
                float val = acc[mt][nt][j] + bv[nt];
                int col = nt * 16 + lr;
                if constexpr (STATS) {
                    if (rv) { s1[nt] += val; s2[nt] += val * val; }
                }
                if (rv && col < ncol_real) {
                    if constexpr (OUTF32)
                        ((float*)Uout)[(size_t)row * ncol_real + col] = val;
                    else
                        ((unsigned short*)Uout)[(size_t)row * 128 + col] = f2b(val);
                }
            }
        }
    }

    if constexpr (STATS) {
        float* slot = stats + (blockIdx.x & 31) * 256;
#pragma unroll
        for (int nt = 0; nt < NT; ++nt) {
            float a = s1[nt], b = s2[nt];
            a += __shfl_xor(a, 16, 64);
            b += __shfl_xor(b, 16, 64);
            a += __shfl_xor(a, 32, 64);
            b += __shfl_xor(b, 32, 64);
            if (lg == 0) {
                atomicAdd(slot + nt * 16 + lr, a);
                atomicAdd(slot + 128 + nt * 16 + lr, b);
            }
        }
    }
}

// ---------------------------------------------------------------- finalize
// a = g*rsqrt(var+eps); d = beta - a*mean   =>  h = relu(a*u + d)
// (kept only for the two agg-consumed stages)
__global__ void bn_finalize_kernel(const float* __restrict__ stats, const float* __restrict__ g,
                                   const float* __restrict__ beta, float* __restrict__ ab) {
    int ci = threadIdx.x;
    float s = 0.f, s2 = 0.f;
    for (int k = 0; k < 32; ++k) {
        s += stats[k * 256 + ci];
        s2 += stats[k * 256 + 128 + ci];
    }
    float m = s * (1.0f / NN);
    float var = s2 * (1.0f / NN) - m * m;
    float a = g[ci] * rsqrtf(var + 1e-5f);
    ab[ci] = a;
    ab[128 + ci] = beta[ci] - a * m;
}

// -------------------------------------------------------------- aggregation
// Z[i] = h(i) + sum_{e: dst=i} w[dist_e] * h(src_e),  h(j) = relu(a*U[j]+d)
// 128 thr = 8 edge-slots (16 lanes each); lane owns 8 cols via one uint4 load.
// Each slot batches 4 gathers (32 outstanding/block). UNCHANGED from R12/R14.
__global__ __launch_bounds__(128) void agg_kernel(const unsigned short* __restrict__ U,
                                                  const int* __restrict__ offsets,
                                                  const int* __restrict__ sorted,
                                                  const float* __restrict__ ab,
                                                  const float* __restrict__ wsm,
                                                  unsigned short* __restrict__ Z) {
    __shared__ int ebuf[128];
    __shared__ float wl[8];
    __shared__ float red[8][128];
    int i = blockIdx.x;
    int t = threadIdx.x;
    int slot = t >> 4;  // 0..7
    int sl = t & 15;    // cols sl*8 .. sl*8+7
    if (t < KK) wl[t] = wsm[t];

    float av[8], dv[8];
#pragma unroll
    for (int j = 0; j < 8; ++j) {
        av[j] = ab[sl * 8 + j];
        dv[j] = ab[128 + sl * 8 + j];
    }

    int beg = offsets[i], end = offsets[i + 1];
    float acc[8] = {};

    for (int base = beg; base < end; base += 128) {
        int n = end - base;
        if (n > 128) n = 128;
        __syncthreads();  // ebuf reuse + wl visibility
        if (t < n) ebuf[t] = sorted[base + t];
        __syncthreads();
        int nfull = n & ~31;
        // bulk: slot takes edges [j0+4*slot .. +3] of each 32-stripe
        for (int j0 = slot * 4; j0 < nfull; j0 += 32) {
            uint4 uu[4];
            float ww[4];
#pragma unroll
            for (int k = 0; k < 4; ++k) {
                int e = ebuf[j0 + k];
                ww[k] = wl[e >> 20];
                uu[k] = *(const uint4*)((const char*)U +
                                        ((unsigned int)(e & 0xFFFFF) << 8) + (sl << 4));
            }
#pragma unroll
            for (int k = 0; k < 4; ++k) {
                acc[0] = fmaf(ww[k], fmaxf(0.f, fmaf(av[0], b2f_lo(uu[k].x), dv[0])), acc[0]);
                acc[1] = fmaf(ww[k], fmaxf(0.f, fmaf(av[1], b2f_hi(uu[k].x), dv[1])), acc[1]);
                acc[2] = fmaf(ww[k], fmaxf(0.f, fmaf(av[2], b2f_lo(uu[k].y), dv[2])), acc[2]);
                acc[3] = fmaf(ww[k], fmaxf(0.f, fmaf(av[3], b2f_hi(uu[k].y), dv[3])), acc[3]);
                acc[4] = fmaf(ww[k], fmaxf(0.f, fmaf(av[4], b2f_lo(uu[k].z), dv[4])), acc[4]);
                acc[5] = fmaf(ww[k], fmaxf(0.f, fmaf(av[5], b2f_hi(uu[k].z), dv[5])), acc[5]);
                acc[6] = fmaf(ww[k], fmaxf(0.f, fmaf(av[6], b2f_lo(uu[k].w), dv[6])), acc[6]);
                acc[7] = fmaf(ww[k], fmaxf(0.f, fmaf(av[7], b2f_hi(uu[k].w), dv[7])), acc[7]);
            }
        }
        // tail: one edge per slot per pass
        for (int j = nfull + slot; j < n; j += 8) {
            int e = ebuf[j];
            float w = wl[e >> 20];
            uint4 u = *(const uint4*)((const char*)U +
                                      ((unsigned int)(e & 0xFFFFF) << 8) + (sl << 4));
            acc[0] = fmaf(w, fmaxf(0.f, fmaf(av[0], b2f_lo(u.x), dv[0])), acc[0]);
            acc[1] = fmaf(w, fmaxf(0.f, fmaf(av[1], b2f_hi(u.x), dv[1])), acc[1]);
            acc[2] = fmaf(w, fmaxf(0.f, fmaf(av[2], b2f_lo(u.y), dv[2])), acc[2]);
            acc[3] = fmaf(w, fmaxf(0.f, fmaf(av[3], b2f_hi(u.y), dv[3])), acc[3]);
            acc[4] = fmaf(w, fmaxf(0.f, fmaf(av[4], b2f_lo(u.z), dv[4])), acc[4]);
            acc[5] = fmaf(w, fmaxf(0.f, fmaf(av[5], b2f_hi(u.z), dv[5])), acc[5]);
            acc[6] = fmaf(w, fmaxf(0.f, fmaf(av[6], b2f_lo(u.w), dv[6])), acc[6]);
            acc[7] = fmaf(w, fmaxf(0.f, fmaf(av[7], b2f_hi(u.w), dv[7])), acc[7]);
        }
    }
    *(f32x4*)(&red[slot][sl * 8]) = (f32x4){acc[0], acc[1], acc[2], acc[3]};
    *(f32x4*)(&red[slot][sl * 8 + 4]) = (f32x4){acc[4], acc[5], acc[6], acc[7]};
    __syncthreads();

    // final: thread t owns column t; sum 8 slots + self term; pack pairs
    float s = 0.f;
#pragma unroll
    for (int s8 = 0; s8 < 8; ++s8) s += red[s8][t];
    float u = b2f(U[((size_t)i << 7) + t]);
    s += fmaxf(0.f, fmaf(ab[t], u, ab[128 + t]));
    float so = __shfl_xor(s, 1, 64);
    if ((t & 1) == 0) {
        unsigned int o = (unsigned int)f2b(s) | ((unsigned int)f2b(so) << 16);
        *(unsigned int*)((char*)Z + ((unsigned int)i << 8) + (t << 1)) = o;
    }
}

// ------------------------------------------------------------------ launch

extern "C" void kernel_launch(void* const* d_in, const int* in_sizes, int n_in,
                              void* d_out, int out_size, void* d_ws, size_t ws_size,
                              hipStream_t stream) {
    const float* x = (const float*)d_in[0];
    const int* ei = (const int*)d_in[1];
    const int* ed = (const int*)d_in[2];
    const float* Wi = (const float*)d_in[3];
    const float* bi = (const float*)d_in[4];
    const float* gi = (const float*)d_in[5];
    const float* bti = (const float*)d_in[6];
    const float* hc0 = (const float*)d_in[7];
    const float* W0a = (const float*)d_in[8];
    const float* b0a = (const float*)d_in[9];
    const float* g0a = (const float*)d_in[10];
    const float* bt0a = (const float*)d_in[11];
    const float* W0b = (const float*)d_in[12];
    const float* b0b = (const float*)d_in[13];
    const float* g0b = (const float*)d_in[14];
    const float* bt0b = (const float*)d_in[15];
    const float* hc1 = (const float*)d_in[16];
    const float* W1a = (const float*)d_in[17];
    const float* b1a = (const float*)d_in[18];
    const float* g1a = (const float*)d_in[19];
    const float* bt1a = (const float*)d_in[20];
    const float* W1b = (const float*)d_in[21];
    const float* b1b = (const float*)d_in[22];
    const float* g1b = (const float*)d_in[23];
    const float* bt1b = (const float*)d_in[24];
    const float* Wp1 = (const float*)d_in[25];
    const float* bp1 = (const float*)d_in[26];
    const float* gp1 = (const float*)d_in[27];
    const float* btp1 = (const float*)d_in[28];
    const float* Wp2 = (const float*)d_in[29];
    const float* bp2 = (const float*)d_in[30];
    float* out = (float*)d_out;

    const int* srcv = ei;
    const int* dstv = ei + EE;

    // workspace layout (all 16B-aligned)
    unsigned short* bufA = (unsigned short*)d_ws;            // N*128 bf16
    unsigned short* bufB = bufA + (size_t)NN * HH;           // N*128 bf16
    unsigned short* wt = bufB + (size_t)NN * HH;             // 7 * 128*128 bf16 (W^T)
    int* sorted = (int*)(wt + 7 * 16384);                    // E int
    int* coarse = sorted + EE;                               // E int (bucketed)
    int* offsets = coarse + EE;                              // N+1 (padded)
    float* stats = (float*)(offsets + NN + 4);               // 6 stages * 32 slots * 256
    float* bnab = stats + 6 * 32 * 256;                      // 2 stages * (a[128], d[128])
    float* wsm = bnab + 2 * 256;                             // 2 softmax sets (stride 8)
    int* gcur = (int*)(wsm + 16);                            // NBUK coarse cursors (512)
    int* bdeg = gcur + 512;                                  // NBUK bucket degrees (512)
    int* bbase = bdeg + 512;                                 // NBUK+1 bucket bases

    // one memset covers stats..bdeg (bnab/wsm/gcur rewritten before use)
    hipMemsetAsync(stats, 0, (size_t)(6 * 32 * 256 + 2 * 256 + 16 + 512 + 512) * 4, stream);

    // CSR build (reused by both layers)
    bucket_hist_kernel<<<(EE + CH2 - 1) / CH2, 512, 0, stream>>>(dstv, bdeg);
    bucket_scan_kernel<<<1, 512, 0, stream>>>(bdeg, bbase, gcur, offsets, hc0, hc1, wsm);
    coarse_scatter_kernel<<<(EE + CH - 1) / CH, 512, 0, stream>>>(srcv, dstv, ed, gcur, coarse);
    fine_scatter_kernel<<<NBUK, 512, 0, stream>>>(coarse, bbase, offsets, sorted);

    prep_w_kernel<<<(7 * 16384 + 255) / 256, 256, 0, stream>>>(Wi, W0a, W0b, W1a, W1b, Wp1, Wp2, wt);

    int gg = (NN + 127) / 128;

    // initial MLP (fp32 x converted in-kernel); stats stage 0 feeds agg0
    mfma_gemm<8, false, true, false, true><<<gg, 256, 0, stream>>>(
        x, wt, bi, 128, nullptr, nullptr, nullptr, bufA, stats);
    bn_finalize_kernel<<<1, 128, 0, stream>>>(stats, gi, bti, bnab);

    // SPN layer 0
    agg_kernel<<<NN, 128, 0, stream>>>(bufA, offsets, sorted, bnab, wsm, bufB);
    mfma_gemm<8, false, true, false, false><<<gg, 256, 0, stream>>>(
        bufB, wt + 16384, b0a, 128, nullptr, nullptr, nullptr, bufA, stats + 8192);
    mfma_gemm<8, true, true, false, false><<<gg, 256, 0, stream>>>(
        bufA, wt + 2 * 16384, b0b, 128, stats + 8192, g0a, bt0a, bufB, stats + 2 * 8192);
    bn_finalize_kernel<<<1, 128, 0, stream>>>(stats + 2 * 8192, g0b, bt0b, bnab + 256);

    // SPN layer 1
    agg_kernel<<<NN, 128, 0, stream>>>(bufB, offsets, sorted, bnab + 256, wsm + 8, bufA);
    mfma_gemm<8, false, true, false, false><<<gg, 256, 0, stream>>>(
        bufA, wt + 3 * 16384, b1a, 128, nullptr, nullptr, nullptr, bufB, stats + 3 * 8192);
    mfma_gemm<8, true, true, false, false><<<gg, 256, 0, stream>>>(
        bufB, wt + 4 * 16384, b1b, 128, stats + 3 * 8192, g1a, bt1a, bufA, stats + 4 * 8192);

    // head
    mfma_gemm<8, true, true, false, false><<<gg, 256, 0, stream>>>(
        bufA, wt + 5 * 16384, bp1, 128, stats + 4 * 8192, g1b, bt1b, bufB, stats + 5 * 8192);
    mfma_gemm<3, true, false, true, false><<<gg, 256, 0, stream>>>(
        bufB, wt + 6 * 16384, bp2, CC, stats + 5 * 8192, gp1, btp1, out, nullptr);

    (void)in_sizes; (void)n_in; (void)out_size; (void)ws_size;
}